// Round 4
// baseline (144.062 us; speedup 1.0000x reference)
//
#include <hip/hip_runtime.h>
#include <hip/hip_bf16.h>

// KAN layer: out = einsum('bik,jik->bj', rbf(x), W) + silu(x)@Wb^T, then LN.
// GEMM view: C[4096,512] = A[4096,8704] * B[512,8704]^T in bf16 MFMA, but A is
// NEVER materialized: each block generates its 128x32 A-tile from x in-kernel
// (rbf basis / silu on the fly) and ds_writes it to LDS. B = [W|Wb] bf16 cast.
//
// K-split balancing: K = 8192 basis + 512 silu = 272 BK=32 iters; 8 z-slices of
// 34 iters each. z<7: pure basis (k0=z*1088, i0=z*68). z=7: 18 basis iters
// (i 476..511) + 16 silu iters (cols 0..511). B rows are contiguous in K for
// every slice, so B staging is identical across z.
//
// d_ws layout (42,467,328 B):
//   Bm bf16 [512][8704]    @ 0        ( 8,912,896 B)
//   Cp bf16 [8][4096][512] @ 8912896  (33,554,432 B)  split-K partials

typedef __bf16 bf16x8 __attribute__((ext_vector_type(8)));
typedef __bf16 bf16x4 __attribute__((ext_vector_type(4)));
typedef float  f32x4  __attribute__((ext_vector_type(4)));

#define KT 8704
#define SPLITS 8
#define NIT 34
#define CPE (4096 * 512)
#define LBUF (128 * 32)

__device__ __forceinline__ void gll16(const __bf16* g, __bf16* l) {
    __builtin_amdgcn_global_load_lds(
        (const __attribute__((address_space(1))) void*)g,
        (__attribute__((address_space(3))) void*)l, 16, 0, 0);
}

__device__ __forceinline__ float fsilu(float t) {
    return t * __builtin_amdgcn_rcpf(1.0f + __expf(-t));
}

// ---- kernel 1: Bm = [W | Wb] cast to bf16 ---------------------------------
__global__ void prep_B(const float* __restrict__ W, const float* __restrict__ Wb,
                       __bf16* __restrict__ B) {
    int t = blockIdx.x * 256 + threadIdx.x;   // 0 .. 512*2176
    int j = t / 2176;
    int c = (t - j * 2176) * 4;
    float4 v;
    if (c < 8192) v = *(const float4*)&W[(size_t)j * 8192 + c];
    else          v = *(const float4*)&Wb[(size_t)j * 512 + (c - 8192)];
    bf16x4 o;
    o[0] = (__bf16)v.x; o[1] = (__bf16)v.y; o[2] = (__bf16)v.z; o[3] = (__bf16)v.w;
    *(bf16x4*)&B[(size_t)j * KT + c] = o;
}

// ---- kernel 2: fused A-gen + split-K GEMM, 128x128, BK=32, dbuf -----------
// LDS chunk swizzle (both A and B): 16B chunk (row, qk) at chunk row*4+(qk^((row>>1)&3)).
// A written via ds_write_b128 (scatter OK); B staged via global_load_lds w16.
__global__ __launch_bounds__(256, 4) void gemm_fused(const float* __restrict__ x,
                                                     const __bf16* __restrict__ B,
                                                     __bf16* __restrict__ Cp) {
    __shared__ __attribute__((aligned(16))) __bf16 As[2 * LBUF];
    __shared__ __attribute__((aligned(16))) __bf16 Bs[2 * LBUF];

    const int tid  = threadIdx.x;
    const int wave = tid >> 6, lane = tid & 63;
    const int q    = lane >> 4, r16 = lane & 15;
    const int m0 = blockIdx.x * 128, n0 = blockIdx.y * 128;
    const int bz = blockIdx.z, k0 = bz * 1088;
    const int wm = wave & 1, wn = wave >> 1;
    const bool zlast = (bz == SPLITS - 1);

    // B staging source (swizzled), two 16B chunks per thread
    const int row0 = tid >> 2, qk0 = (tid & 3) ^ ((row0 >> 1) & 3);
    const int row1 = row0 + 64, qk1 = (tid & 3) ^ ((row1 >> 1) & 3);
    const __bf16* gB0 = B + (size_t)(n0 + row0) * KT + k0 + qk0 * 8;
    const __bf16* gB1 = B + (size_t)(n0 + row1) * KT + k0 + qk1 * 8;

    // A generation: thread -> (arow = tid>>1, p = tid&1); produces k-local
    // p*16+0..15 (kappa 0..15 of i = i0+it*2+p, or silu cols c..c+15).
    const int arow = tid >> 1, p = tid & 1;
    const int sw = (arow >> 1) & 3;
    const int c0 = arow * 4 + ((2 * p)     ^ sw);   // chunk for kappa 0..7
    const int c1 = arow * 4 + ((2 * p + 1) ^ sw);   // chunk for kappa 8..15
    const float* xr = x + (size_t)(m0 + arow) * 512;
    const int i0 = bz * 68;

    f32x4 acc[4][4] = {};
    const int qa = q ^ ((r16 >> 1) & 3);            // de-swizzle for frag reads
    const int awOff = (wm * 64 + r16) * 32 + qa * 8;
    const int bwOff = (wn * 64 + r16) * 32 + qa * 8;

    // ---- prologue: tile 0 (always basis) into buffer 0
    {
        float xv = xr[i0 + p];
        float zb = 3.75f * xv + 7.5f;                // z_k = zb - k, centers k=0..15
        bf16x8 v;
#pragma unroll
        for (int j = 0; j < 8; ++j) { float d = zb - (float)j; v[j] = (__bf16)__expf(-d * d); }
        *(bf16x8*)&As[c0 * 8] = v;
#pragma unroll
        for (int j = 8; j < 16; ++j) { float d = zb - (float)j; v[j - 8] = (__bf16)__expf(-d * d); }
        *(bf16x8*)&As[c1 * 8] = v;
        gll16(gB0, &Bs[tid * 8]);
        gll16(gB1, &Bs[(tid + 256) * 8]);
    }
    float xv_pipe = xr[i0 + 2 + p];                  // prefetch x for itn=1 (basis)
    __syncthreads();

    for (int it = 0; it < NIT; ++it) {
        const int itn = it + 1;
        if (itn < NIT) {                             // prepare next tile
            const int sb = (itn & 1) * LBUF;
            gll16(gB0 + itn * 32, &Bs[sb + tid * 8]);
            gll16(gB1 + itn * 32, &Bs[sb + (tid + 256) * 8]);
            if (zlast && itn >= 18) {                // silu region (z=7 only)
                const int c = (itn - 18) * 32 + p * 16;
                float4 a0 = *(const float4*)&xr[c];
                float4 a1 = *(const float4*)&xr[c + 4];
                bf16x8 v;
                v[0] = (__bf16)fsilu(a0.x); v[1] = (__bf16)fsilu(a0.y);
                v[2] = (__bf16)fsilu(a0.z); v[3] = (__bf16)fsilu(a0.w);
                v[4] = (__bf16)fsilu(a1.x); v[5] = (__bf16)fsilu(a1.y);
                v[6] = (__bf16)fsilu(a1.z); v[7] = (__bf16)fsilu(a1.w);
                *(bf16x8*)&As[sb + c0 * 8] = v;
                float4 a2 = *(const float4*)&xr[c + 8];
                float4 a3 = *(const float4*)&xr[c + 12];
                v[0] = (__bf16)fsilu(a2.x); v[1] = (__bf16)fsilu(a2.y);
                v[2] = (__bf16)fsilu(a2.z); v[3] = (__bf16)fsilu(a2.w);
                v[4] = (__bf16)fsilu(a3.x); v[5] = (__bf16)fsilu(a3.y);
                v[6] = (__bf16)fsilu(a3.z); v[7] = (__bf16)fsilu(a3.w);
                *(bf16x8*)&As[sb + c1 * 8] = v;
            } else {                                 // basis region
                float zb = 3.75f * xv_pipe + 7.5f;
                bf16x8 v;
#pragma unroll
                for (int j = 0; j < 8; ++j) { float d = zb - (float)j; v[j] = (__bf16)__expf(-d * d); }
                *(bf16x8*)&As[sb + c0 * 8] = v;
#pragma unroll
                for (int j = 8; j < 16; ++j) { float d = zb - (float)j; v[j - 8] = (__bf16)__expf(-d * d); }
                *(bf16x8*)&As[sb + c1 * 8] = v;
                if (itn + 1 < NIT && !(zlast && itn + 1 >= 18))
                    xv_pipe = xr[i0 + (itn + 1) * 2 + p];   // always in-bounds
            }
        }
        // compute on buffer it&1
        const int cb = (it & 1) * LBUF;
        const __bf16* Aw = &As[cb + awOff];
        const __bf16* Bw = &Bs[cb + bwOff];
        bf16x8 af[4], bg[4];
#pragma unroll
        for (int mi = 0; mi < 4; ++mi) af[mi] = *(const bf16x8*)(Aw + mi * 512);
#pragma unroll
        for (int ni = 0; ni < 4; ++ni) bg[ni] = *(const bf16x8*)(Bw + ni * 512);
#pragma unroll
        for (int mi = 0; mi < 4; ++mi)
#pragma unroll
            for (int ni = 0; ni < 4; ++ni)
                acc[mi][ni] = __builtin_amdgcn_mfma_f32_16x16x32_bf16(
                    af[mi], bg[ni], acc[mi][ni], 0, 0, 0);
        __syncthreads();   // drains DMA + ds_writes (covered by MFMA above), guards dbuf
    }

    // epilogue: C/D layout col=lane&15, row=(lane>>4)*4+reg; bf16 partials
    __bf16* Cb = Cp + (size_t)bz * CPE;
#pragma unroll
    for (int mi = 0; mi < 4; ++mi) {
        const int row = m0 + wm * 64 + mi * 16 + q * 4;
#pragma unroll
        for (int ni = 0; ni < 4; ++ni) {
            const int col = n0 + wn * 64 + ni * 16 + r16;
#pragma unroll
            for (int r = 0; r < 4; ++r)
                Cb[(size_t)(row + r) * 512 + col] = (__bf16)acc[mi][ni][r];
        }
    }
}

// ---- kernel 3: sum 8 bf16 partials + LayerNorm, one wave per row ----------
__global__ void ln_kernel(const __bf16* __restrict__ Cp, const float* __restrict__ gamma,
                          const float* __restrict__ beta, float* __restrict__ out) {
    const int tid  = threadIdx.x;
    const int wave = tid >> 6, lane = tid & 63;
    const int row  = blockIdx.x * 4 + wave;
    const size_t base = (size_t)row * 512 + lane * 8;

    float v[8] = {};
    float s = 0.f, s2 = 0.f;
#pragma unroll
    for (int z = 0; z < SPLITS; ++z) {
        bf16x8 pv = *(const bf16x8*)(Cp + (size_t)z * CPE + base);
#pragma unroll
        for (int j = 0; j < 8; ++j) v[j] += (float)pv[j];
    }
#pragma unroll
    for (int j = 0; j < 8; ++j) { s += v[j]; s2 += v[j] * v[j]; }
#pragma unroll
    for (int m = 32; m >= 1; m >>= 1) {
        s  += __shfl_xor(s, m);
        s2 += __shfl_xor(s2, m);
    }
    const float mean = s * (1.0f / 512.0f);
    const float var  = s2 * (1.0f / 512.0f) - mean * mean;
    const float rs   = rsqrtf(var + 1e-5f);
    float4 o0, o1;
    const float4 g0 = *(const float4*)&gamma[lane * 8];
    const float4 g1 = *(const float4*)&gamma[lane * 8 + 4];
    const float4 b0 = *(const float4*)&beta[lane * 8];
    const float4 b1 = *(const float4*)&beta[lane * 8 + 4];
    o0.x = (v[0] - mean) * rs * g0.x + b0.x;
    o0.y = (v[1] - mean) * rs * g0.y + b0.y;
    o0.z = (v[2] - mean) * rs * g0.z + b0.z;
    o0.w = (v[3] - mean) * rs * g0.w + b0.w;
    o1.x = (v[4] - mean) * rs * g1.x + b1.x;
    o1.y = (v[5] - mean) * rs * g1.y + b1.y;
    o1.z = (v[6] - mean) * rs * g1.z + b1.z;
    o1.w = (v[7] - mean) * rs * g1.w + b1.w;
    *(float4*)&out[base]     = o0;
    *(float4*)&out[base + 4] = o1;
}

extern "C" void kernel_launch(void* const* d_in, const int* in_sizes, int n_in,
                              void* d_out, int out_size, void* d_ws, size_t ws_size,
                              hipStream_t stream) {
    const float* x     = (const float*)d_in[0];
    const float* W     = (const float*)d_in[1];
    const float* Wb    = (const float*)d_in[2];
    const float* gamma = (const float*)d_in[3];
    const float* beta  = (const float*)d_in[4];
    float* out = (float*)d_out;

    char* ws = (char*)d_ws;
    __bf16* Bm = (__bf16*)ws;                 //  8,912,896 B
    __bf16* Cp = (__bf16*)(ws + 8912896);     // 33,554,432 B

    prep_B<<<4352, 256, 0, stream>>>(W, Wb, Bm);
    dim3 g(32, 4, SPLITS);
    gemm_fused<<<g, 256, 0, stream>>>(x, Bm, Cp);
    ln_kernel<<<1024, 256, 0, stream>>>(Cp, gamma, beta, out);
}